// Round 6
// baseline (483.731 us; speedup 1.0000x reference)
//
#include <hip/hip_runtime.h>
#include <hip/hip_bf16.h>

// DCell forward, bf16-MFMA. Round-6 structure:
//  - pack_ain0/pack_ain1: x fp32 -> zero-padded bf16 GEMM-A rows (ain0 holds a
//    full bf16 x copy at col 1232 that the small GEMMs also read genes from).
//  - s4/s3/s2: gemm_small (VGPR staging, all-bf16 sources).
//  - s1/s0: gemm_split BK=64 (32 MFMA per barrier window), 128-row tiles,
//    global_load_lds(16B), XOR-swizzled LDS (pos = kg ^ (row&7), 2-way max),
//    split-K fp32 partials; reduce_bias_stats fuses reduce+bias+h+stats.
//  - Stats: per-chunk partial sums [16][2*TO] (no atomics/memsets) ->
//    bn_scale16 -> per-col scale/shift -> tanh kernels (vec for O=20 stages,
//    wave variant for s2/s1/s0). fast_tanh = exp2+rcp (~1e-7 err).
// Stages (T, I, O, C, Gs): s4(256,16,20,0,16) s3(64,144,20,80,64)
//  s2(16,336,77,80,256) s1(4,1332,308,308,1024) s0(1,5328,1229,1232,4096)

#define BDIM 2048
#define OUTW 341

typedef __attribute__((ext_vector_type(8))) short short8;   // 8 bf16 = 4 VGPRs
typedef __attribute__((ext_vector_type(4))) float float4v;  // MFMA acc

static __device__ __forceinline__ unsigned short f2bf(float f) {
    union { float f; unsigned u; } c{f};
    unsigned r = c.u + 0x7FFF + ((c.u >> 16) & 1);  // RNE
    return (unsigned short)(r >> 16);
}
static __device__ __forceinline__ float bf2f(unsigned short s) {
    union { unsigned u; float f; } c{(unsigned)s << 16};
    return c.f;
}

// tanh via v_exp_f32 + v_rcp_f32: ~7 VALU ops, ~1e-7 rel error.
static __device__ __forceinline__ float fast_tanh(float x) {
    float ax = __builtin_fabsf(x);
    float e  = __builtin_amdgcn_exp2f(ax * 2.8853900817779268f);  // e^{2|x|}
    float r  = 1.f - 2.f * __builtin_amdgcn_rcpf(e + 1.f);
    return __builtin_copysignf(r, x);
}

// async global->LDS, 16B/lane. LDS dest semantics: wave-uniform base + lane*16.
static __device__ __forceinline__ void stage16(const void* g, void* ldsBase, int lane) {
#if __has_builtin(__builtin_amdgcn_global_load_lds)
    __builtin_amdgcn_global_load_lds(
        (const __attribute__((address_space(1))) unsigned int*)(uintptr_t)g,
        (__attribute__((address_space(3))) unsigned int*)(unsigned int)(uintptr_t)ldsBase,
        16, 0, 0);
#else
    *(uint4*)((char*)ldsBase + lane * 16) = *(const uint4*)g;
#endif
}

// ---- pack x (fp32) -> Ain0[b][5376]: cols [1232,5328)=x genes bf16, [5328,5376)=0
__global__ __launch_bounds__(256) void pack_ain0(const float* __restrict__ x,
                                                 unsigned short* __restrict__ ain0) {
    const int GPR = 518;  // 16B granules per row
    int i = blockIdx.x * 256 + threadIdx.x;
    if (i >= BDIM * GPR) return;
    int b = i / GPR, g = i % GPR;
    unsigned short* dst = ain0 + (size_t)b * 5376 + 1232 + g * 8;
    if (g < 512) {
        const float* xp = x + (size_t)b * 4096 + g * 8;
        float4 lo = *(const float4*)xp, hi = *(const float4*)(xp + 4);
        union { unsigned short u[8]; uint4 v; } t;
        t.u[0] = f2bf(lo.x); t.u[1] = f2bf(lo.y); t.u[2] = f2bf(lo.z); t.u[3] = f2bf(lo.w);
        t.u[4] = f2bf(hi.x); t.u[5] = f2bf(hi.y); t.u[6] = f2bf(hi.z); t.u[7] = f2bf(hi.w);
        *(uint4*)dst = t.v;
    } else {
        *(uint4*)dst = make_uint4(0u, 0u, 0u, 0u);
    }
}

// ---- pack x -> Ain1[b][t*1344 + 308 .. ]: genes at [308,1332), zeros [1332,1344)
__global__ __launch_bounds__(256) void pack_ain1(const float* __restrict__ x,
                                                 unsigned short* __restrict__ ain1) {
    const int UPT = 259;  // 4-elem units per term
    int i = blockIdx.x * 256 + threadIdx.x;
    if (i >= BDIM * 4 * UPT) return;
    int b = i / (4 * UPT), rem = i % (4 * UPT), t = rem / UPT, u = rem % UPT;
    unsigned short* dst = ain1 + (size_t)b * 5376 + t * 1344 + 308 + u * 4;
    if (u < 256) {
        float4 v = *(const float4*)(x + (size_t)b * 4096 + t * 1024 + u * 4);
        union { unsigned short s[4]; uint2 v; } p;
        p.s[0] = f2bf(v.x); p.s[1] = f2bf(v.y); p.s[2] = f2bf(v.z); p.s[3] = f2bf(v.w);
        *(uint2*)dst = p.v;
    } else {
        *(uint2*)dst = make_uint2(0u, 0u);
    }
}

// ---- W[t][I][O] fp32 -> WbT[t][Npad][Kpad] bf16 (rows o>=O and k>=I zeroed) ----
__global__ __launch_bounds__(256) void cvt_w(const float* __restrict__ W,
                                             unsigned short* __restrict__ WbT,
                                             int I, int O, int Npad, int Kpad) {
    __shared__ unsigned short tile[32][33];
    const int t = blockIdx.z;
    const int i0 = blockIdx.x * 32, o0 = blockIdx.y * 32;
    const int c = threadIdx.x & 31, r0 = threadIdx.x >> 5;
    const float* Wt = W + (size_t)t * I * O;
    #pragma unroll
    for (int rr = 0; rr < 4; rr++) {
        int i = i0 + r0 + rr * 8, o = o0 + c;
        float v = (i < I && o < O) ? Wt[(size_t)i * O + o] : 0.f;
        tile[r0 + rr * 8][c] = f2bf(v);
    }
    __syncthreads();
    unsigned short* dst = WbT + (size_t)t * Npad * Kpad;
    #pragma unroll
    for (int rr = 0; rr < 4; rr++) {
        int o = o0 + r0 + rr * 8, k = i0 + c;
        if (o < Npad) dst[(size_t)o * Kpad + k] = tile[c][r0 + rr * 8];
    }
}

// ---- small-stage GEMM (s4/s3/s2): VGPR staging, all-bf16 sources ----
// gene source xg = bf16 x copy (row stride 5376), genes for term t at xg + t*Gs.
template <int BN, int BK>
__global__ __launch_bounds__(256) void gemm_small(
    const unsigned short* __restrict__ actb,  // [B][T*C] bf16 (null if C==0)
    const unsigned short* __restrict__ xg,    // bf16 x copy, row stride 5376
    const unsigned short* __restrict__ WbT,   // [T][O][Kpad] bf16
    const float* __restrict__ bias,
    unsigned short* __restrict__ h,           // [B][hstride]
    int T, int I, int O, int C, int Gs, int Kpad, int hstride)
{
    const int t  = blockIdx.z;
    const int b0 = blockIdx.y * 64;
    const int o0 = blockIdx.x * BN;
    const int tid = threadIdx.x;
    const int lane = tid & 63;
    const int w = tid >> 6;
    const int l15 = lane & 15;
    const int quad = lane >> 4;

    constexpr int NF = BN / 32;
    const int wm = (w & 1) * 32;
    const int wn = (w >> 1) * (BN / 2);

    __shared__ __align__(16) unsigned short As[64][BK + 8];
    __shared__ __align__(16) unsigned short Bs[BN][BK + 8];

    float4v acc[2][NF];
    #pragma unroll
    for (int a = 0; a < 2; a++)
        #pragma unroll
        for (int b = 0; b < NF; b++)
            acc[a][b] = (float4v){0.f, 0.f, 0.f, 0.f};

    constexpr int GR = BK / 8;
    constexpr int AG = 64 * GR;
    constexpr int BG = BN * GR;
    const size_t actRow = (size_t)T * C;

    for (int k0 = 0; k0 < Kpad; k0 += BK) {
        #pragma unroll
        for (int g = tid; g < AG; g += 256) {
            const int r = g / GR, c8 = g % GR;
            const int k = k0 + c8 * 8;
            const int b = b0 + r;
            uint4 v;
            if (k + 8 <= C) {             // act region (granule-aligned: C%8==0)
                v = *(const uint4*)(actb + (size_t)b * actRow + (size_t)t * C + k);
            } else if (k >= I) {
                v = make_uint4(0u, 0u, 0u, 0u);
            } else {                      // gene region, bf16 copy (I-C multiple of 8)
                v = *(const uint4*)(xg + (size_t)b * 5376 + (size_t)t * Gs + (k - C));
            }
            *(uint4*)&As[r][c8 * 8] = v;
        }
        #pragma unroll
        for (int g = tid; g < BG; g += 256) {
            const int n = g / GR, c8 = g % GR;
            const int o = o0 + n;
            uint4 v = make_uint4(0u, 0u, 0u, 0u);
            if (o < O)
                v = *(const uint4*)(WbT + ((size_t)t * O + o) * Kpad + k0 + c8 * 8);
            *(uint4*)&Bs[n][c8 * 8] = v;
        }
        __syncthreads();
        #pragma unroll
        for (int ks = 0; ks < BK / 32; ks++) {
            const int koff = ks * 32 + quad * 8;
            short8 a0 = *(const short8*)&As[wm + l15][koff];
            short8 a1 = *(const short8*)&As[wm + 16 + l15][koff];
            #pragma unroll
            for (int fn = 0; fn < NF; fn++) {
                short8 bf = *(const short8*)&Bs[wn + fn * 16 + l15][koff];
                acc[0][fn] = __builtin_amdgcn_mfma_f32_16x16x32_bf16(a0, bf, acc[0][fn], 0, 0, 0);
                acc[1][fn] = __builtin_amdgcn_mfma_f32_16x16x32_bf16(a1, bf, acc[1][fn], 0, 0, 0);
            }
        }
        __syncthreads();
    }

    #pragma unroll
    for (int fm = 0; fm < 2; fm++)
        #pragma unroll
        for (int fn = 0; fn < NF; fn++)
            #pragma unroll
            for (int r = 0; r < 4; r++) {
                int m = wm + fm * 16 + quad * 4 + r;
                int o = o0 + wn + fn * 16 + l15;
                if (o < O) {
                    float v = acc[fm][fn][r] + bias[t * O + o];
                    h[(size_t)(b0 + m) * hstride + (size_t)t * O + o] = f2bf(v);
                }
            }
}

// ---- big-stage GEMM (s1/s0): 128-row tile, BK=64, global_load_lds, split-K ----
// LDS slot layout: slot = row*8 + pos, pos = kg ^ (row&7)  => <=2-way bank alias.
template <int BN>
__global__ __launch_bounds__(256) void gemm_split(
    const unsigned short* __restrict__ A,     // [2048][aStride] bf16 (zero-padded)
    const unsigned short* __restrict__ WbT,   // [T][Npad][Kpad] bf16 (zero-padded)
    float* __restrict__ partial,              // [KS][2048][TNpad]
    int aStride, int tStride, int Kpad, int Npad, int KS, int TNpad)
{
    const int tid = threadIdx.x;
    const int lane = tid & 63, w = tid >> 6;
    const int l15 = lane & 15, quad = lane >> 4;
    const int n0 = blockIdx.x * BN;
    const int b0 = blockIdx.y * 128;
    const int ksIdx = blockIdx.z % KS;
    const int t = blockIdx.z / KS;

    __shared__ __align__(16) unsigned short As[128 * 64];   // 16 KB
    __shared__ __align__(16) unsigned short Bs[BN * 64];    // 16/8 KB

    const int S = Kpad >> 6;            // 64-wide K steps
    const int qb = S / KS, rb = S % KS;
    const int beg = ksIdx * qb + (ksIdx < rb ? ksIdx : rb);
    const int cnt = qb + (ksIdx < rb ? 1 : 0);

    constexpr int NF = BN / 32;
    const int wm = (w & 1) * 64;
    const int wn = (w >> 1) * (BN / 2);

    float4v acc[4][NF];
    #pragma unroll
    for (int a = 0; a < 4; a++)
        #pragma unroll
        for (int b = 0; b < NF; b++)
            acc[a][b] = (float4v){0.f, 0.f, 0.f, 0.f};

    // A staging: 1024 slots (128 rows x 8 granules), 4 calls/wave.
    const unsigned short* aSrc[4];
    unsigned short* aDst[4];
    #pragma unroll
    for (int j = 0; j < 4; j++) {
        int s = w * 256 + j * 64 + lane;
        int r = s >> 3, pos = s & 7;
        int kg = pos ^ (r & 7);
        aSrc[j] = A + (size_t)(b0 + r) * aStride + (size_t)t * tStride + kg * 8;
        aDst[j] = &As[(size_t)(w * 256 + j * 64 - lane) * 8 + (size_t)lane * 8]; // = slot base
    }
    // B staging: BN*8 slots, BC calls/wave.
    constexpr int BC = (BN == 128) ? 4 : 2;
    const unsigned short* bSrc[BC];
    unsigned short* bDst[BC];
    #pragma unroll
    for (int j = 0; j < BC; j++) {
        int s = w * (BC * 64) + j * 64 + lane;
        int r = s >> 3, pos = s & 7;
        int kg = pos ^ (r & 7);
        bSrc[j] = WbT + ((size_t)t * Npad + n0 + r) * Kpad + kg * 8;
        bDst[j] = &Bs[(size_t)(w * (BC * 64) + j * 64) * 8];
    }
    #pragma unroll
    for (int j = 0; j < 4; j++) aDst[j] = &As[(size_t)(w * 256 + j * 64) * 8];

    for (int sI = 0; sI < cnt; sI++) {
        const int k0 = (beg + sI) << 6;
        __syncthreads();                       // prev MFMA reads done before overwrite
        #pragma unroll
        for (int j = 0; j < 4; j++)  stage16(aSrc[j] + k0, aDst[j], lane);
        #pragma unroll
        for (int j = 0; j < BC; j++) stage16(bSrc[j] + k0, bDst[j], lane);
        __syncthreads();                       // drains vmcnt -> LDS ready

        #pragma unroll
        for (int ks = 0; ks < 2; ks++) {
            const int kq = ks * 4 + quad;      // granule within row
            short8 af[4];
            #pragma unroll
            for (int fm = 0; fm < 4; fm++) {
                int m = wm + fm * 16 + l15;
                af[fm] = *(const short8*)&As[m * 64 + (kq ^ (m & 7)) * 8];
            }
            short8 bfr[NF];
            #pragma unroll
            for (int fn = 0; fn < NF; fn++) {
                int n = wn + fn * 16 + l15;
                bfr[fn] = *(const short8*)&Bs[n * 64 + (kq ^ (n & 7)) * 8];
            }
            #pragma unroll
            for (int fm = 0; fm < 4; fm++)
                #pragma unroll
                for (int fn = 0; fn < NF; fn++)
                    acc[fm][fn] = __builtin_amdgcn_mfma_f32_16x16x32_bf16(af[fm], bfr[fn], acc[fm][fn], 0, 0, 0);
        }
    }

    const size_t pBase = ((size_t)ksIdx * BDIM + b0) * TNpad + (size_t)t * Npad + n0;
    #pragma unroll
    for (int fm = 0; fm < 4; fm++)
        #pragma unroll
        for (int r = 0; r < 4; r++) {
            const int m = wm + fm * 16 + quad * 4 + r;
            float* prow = partial + pBase + (size_t)m * TNpad + wn;
            #pragma unroll
            for (int fn = 0; fn < NF; fn++)
                prow[fn * 16 + l15] = acc[fm][fn][r];
        }
}

// ---- fused split-K reduce + bias + bf16 h store + per-chunk stats partials ----
// grid (ceil(TO/64), 16); thread = (cr = tid>>6 row quarter, colL = tid&63).
__global__ __launch_bounds__(256) void reduce_bias_stats(
    const float* __restrict__ partial, const float* __restrict__ bias,
    unsigned short* __restrict__ h, float* __restrict__ sp,
    int T, int O, int Npad, int KS, int hstride, int TO)
{
    __shared__ float redS[4][64], redS2[4][64];
    const int colL = threadIdx.x & 63;
    const int cr = threadIdx.x >> 6;
    const int col = blockIdx.x * 64 + colL;
    const int chunk = blockIdx.y;
    float s = 0.f, s2 = 0.f;
    if (col < TO) {
        int t = col / O, o = col - t * O;
        const size_t TNpad = (size_t)T * Npad;
        const size_t pcol = (size_t)t * Npad + o;
        const float bv = bias[col];
        const int row0 = chunk * 128 + cr * 32;
        for (int r = 0; r < 32; r++) {
            const int row = row0 + r;
            const float* p = partial + (size_t)row * TNpad + pcol;
            float v = bv;
            for (int ks = 0; ks < KS; ks++) v += p[(size_t)ks * BDIM * TNpad];
            h[(size_t)row * hstride + col] = f2bf(v);
            s += v; s2 += v * v;
        }
    }
    redS[cr][colL] = s; redS2[cr][colL] = s2;
    __syncthreads();
    if (cr == 0 && col < TO) {
        float ts  = redS[0][colL] + redS[1][colL] + redS[2][colL] + redS[3][colL];
        float ts2 = redS2[0][colL] + redS2[1][colL] + redS2[2][colL] + redS2[3][colL];
        sp[(size_t)chunk * 2 * TO + col] = ts;
        sp[(size_t)chunk * 2 * TO + TO + col] = ts2;
    }
}

// ---- per-chunk stats partials from bf16 h (no atomics, no memset) ----
__global__ __launch_bounds__(256) void bn_stats_part(const unsigned short* __restrict__ h,
                                                     float* __restrict__ sp,
                                                     int TO, int hstride) {
    int col = blockIdx.x * 256 + threadIdx.x;
    if (col >= TO) return;
    const int chunk = blockIdx.y;
    const unsigned short* p = h + (size_t)chunk * 128 * hstride + col;
    float s = 0.f, s2 = 0.f;
    #pragma unroll 4
    for (int b = 0; b < 128; b++) {
        float v = bf2f(p[(size_t)b * hstride]);
        s += v; s2 += v * v;
    }
    sp[(size_t)chunk * 2 * TO + col] = s;
    sp[(size_t)chunk * 2 * TO + TO + col] = s2;
}

// ---- fold 16 chunk partials -> per-col scale/shift ----
__global__ __launch_bounds__(256) void bn_scale16(const float* __restrict__ sp,
                                                  const float* __restrict__ g,
                                                  const float* __restrict__ bb,
                                                  float* __restrict__ ss, int TO) {
    int col = blockIdx.x * 256 + threadIdx.x;
    if (col >= TO) return;
    float s = 0.f, s2 = 0.f;
    #pragma unroll
    for (int c = 0; c < 16; c++) {
        s  += sp[(size_t)c * 2 * TO + col];
        s2 += sp[(size_t)c * 2 * TO + TO + col];
    }
    float mu = s * (1.f / BDIM);
    float var = s2 * (1.f / BDIM) - mu * mu;  // biased, matches jnp.var
    float scale = rsqrtf(var + 1e-5f) * g[col];
    ss[col] = scale;
    ss[TO + col] = bb[col] - mu * scale;
}

// ---- vectorized BN+tanh+head for O=20 in-place stages (s4/s3) ----
template <int GPT>
__global__ __launch_bounds__(256) void bn_tanh_head_vec(
    unsigned short* hact,                    // in: h, out: act (in place)
    const float* __restrict__ ss,            // [hstride]=scale, [hstride..)=shift
    const float* __restrict__ hw, const float* __restrict__ hb,
    float* __restrict__ out,
    int T, int rowGran, int RPB, int hstride, int head_off)
{
    __shared__ float headAcc[256];
    const int tid = threadIdx.x;
    headAcc[tid] = 0.f;
    __syncthreads();
    const int b0 = blockIdx.x * RPB;

    uint2 hv[GPT];
    #pragma unroll
    for (int j = 0; j < GPT; j++) {
        int G = tid + j * 256;
        int r = G / rowGran, gg = G % rowGran;
        hv[j] = *(const uint2*)(hact + (size_t)(b0 + r) * hstride + gg * 4);
    }
    #pragma unroll
    for (int j = 0; j < GPT; j++) {
        int G = tid + j * 256;
        int r = G / rowGran, gg = G % rowGran;
        int c = gg * 4;
        float4 sc = *(const float4*)(ss + c);
        float4 sh = *(const float4*)(ss + hstride + c);
        float4 w4 = *(const float4*)(hw + c);
        union { unsigned short u[4]; uint2 v; } iv, ov;
        iv.v = hv[j];
        float a0 = fast_tanh(bf2f(iv.u[0]) * sc.x + sh.x);
        float a1 = fast_tanh(bf2f(iv.u[1]) * sc.y + sh.y);
        float a2 = fast_tanh(bf2f(iv.u[2]) * sc.z + sh.z);
        float a3 = fast_tanh(bf2f(iv.u[3]) * sc.w + sh.w);
        ov.u[0] = f2bf(a0); ov.u[1] = f2bf(a1); ov.u[2] = f2bf(a2); ov.u[3] = f2bf(a3);
        *(uint2*)(hact + (size_t)(b0 + r) * hstride + c) = ov.v;
        float partial = a0 * w4.x + a1 * w4.y + a2 * w4.z + a3 * w4.w;
        int t = gg / 5;   // 5 granules per term (O=20)
        atomicAdd(&headAcc[r * T + t], partial);
    }
    __syncthreads();
    if (tid < RPB * T) {
        int r = tid / T, t = tid % T;
        out[(size_t)(b0 + r) * OUTW + head_off + t] = headAcc[tid] + hb[t];
    }
}

// ---- BN + tanh + strided act store + head — WAVE variant (scale/shift input) ----
__global__ __launch_bounds__(256) void bn_tanh_head(
    const unsigned short* __restrict__ h, const float* __restrict__ ss,
    const float* __restrict__ hw, const float* __restrict__ hb,
    unsigned short* __restrict__ actOut, float* __restrict__ out,
    int T, int O, int hstride, int aRow, int GT, int GS, int head_off, int TO)
{
    int wid  = (blockIdx.x * 256 + threadIdx.x) >> 6;
    int lane = threadIdx.x & 63;
    int b = wid / T;
    int t = wid % T;
    const size_t hbase = (size_t)b * hstride + (size_t)t * O;
    const size_t abase = (size_t)b * aRow + (size_t)(t / GT) * GS + (size_t)(t % GT) * O;
    float hsum = 0.f;
    for (int o = lane; o < O; o += 64) {
        int col = t * O + o;
        float a = fast_tanh(bf2f(h[hbase + o]) * ss[col] + ss[TO + col]);
        actOut[abase + o] = f2bf(a);
        hsum += a * hw[col];
    }
    #pragma unroll
    for (int off = 32; off > 0; off >>= 1) hsum += __shfl_down(hsum, off, 64);
    if (lane == 0) out[(size_t)b * OUTW + head_off + t] = hsum + hb[t];
}

extern "C" void kernel_launch(void* const* d_in, const int* in_sizes, int n_in,
                              void* d_out, int out_size, void* d_ws, size_t ws_size,
                              hipStream_t stream)
{
    const float* x = (const float*)d_in[0];
    float* out = (float*)d_out;
    char* ws = (char*)d_ws;

    // ws layout (bytes); total ~89.8 MB
    unsigned short* wbt  = (unsigned short*)(ws);              // 13,762,560 (s0 WbT max)
    unsigned short* ain0 = (unsigned short*)(ws + 13762560);   // 22,020,096 (2048x5376)
    unsigned short* bufA = (unsigned short*)(ws + 35782656);   // 20,971,520 (h4/act4 2048x5120)
    unsigned short* bufB = (unsigned short*)(ws + 56754176);   //  5,242,880 (h3/act3 2048x1280)
    unsigned short* ain1 = (unsigned short*)(ws + 61997056);   // 22,020,096 (2048x5376)
    unsigned short* bufC = (unsigned short*)(ws + 84017152);   //  5,046,272 (h2/h1/h0 2048x1232)
    float*          sp   = (float*)(ws + 89063424);            //    655,360 (16 x 2 x 5120)
    float*          ss   = (float*)(ws + 89718784);            //     40,960 (2 x 5120)
    // split-K partials overlay bufA.. (dead by use time): s1 20.9MB, s0 41.9MB
    float* partial = (float*)(ws + 35782656);
    unsigned short* xg = ain0 + 1232;  // full bf16 x copy, row stride 5376

    pack_ain0<<<(BDIM * 518 + 255) / 256, 256, 0, stream>>>(x, ain0);
    pack_ain1<<<(BDIM * 4 * 259 + 255) / 256, 256, 0, stream>>>(x, ain1);

    const float* W4 = (const float*)d_in[1];  const float* b4 = (const float*)d_in[2];
    const float* g4 = (const float*)d_in[3];  const float* bb4 = (const float*)d_in[4];
    const float* hw4 = (const float*)d_in[5]; const float* hb4 = (const float*)d_in[6];
    const float* W3 = (const float*)d_in[7];  const float* b3 = (const float*)d_in[8];
    const float* g3 = (const float*)d_in[9];  const float* bb3 = (const float*)d_in[10];
    const float* hw3 = (const float*)d_in[11]; const float* hb3 = (const float*)d_in[12];
    const float* W2 = (const float*)d_in[13]; const float* b2 = (const float*)d_in[14];
    const float* g2 = (const float*)d_in[15]; const float* bb2 = (const float*)d_in[16];
    const float* hw2 = (const float*)d_in[17]; const float* hb2 = (const float*)d_in[18];
    const float* W1 = (const float*)d_in[19]; const float* b1 = (const float*)d_in[20];
    const float* g1 = (const float*)d_in[21]; const float* bb1 = (const float*)d_in[22];
    const float* hw1 = (const float*)d_in[23]; const float* hb1 = (const float*)d_in[24];
    const float* W0 = (const float*)d_in[25]; const float* b0_ = (const float*)d_in[26];
    const float* g0 = (const float*)d_in[27]; const float* bb0 = (const float*)d_in[28];
    const float* hw0 = (const float*)d_in[29]; const float* hb0 = (const float*)d_in[30];

    // ---------------- s4: T=256 I=16 O=20 C=0 Gs=16 Kpad=32 ----------------
    cvt_w<<<dim3(1, 1, 256), 256, 0, stream>>>(W4, wbt, 16, 20, 20, 32);
    gemm_small<32, 32><<<dim3(1, 32, 256), 256, 0, stream>>>(nullptr, xg, wbt, b4, bufA,
                                                             256, 16, 20, 0, 16, 32, 5120);
    bn_stats_part<<<dim3(20, 16), 256, 0, stream>>>(bufA, sp, 5120, 5120);
    bn_scale16<<<20, 256, 0, stream>>>(sp, g4, bb4, ss, 5120);
    bn_tanh_head_vec<5><<<BDIM, 256, 0, stream>>>(bufA, ss, hw4, hb4, out,
                                                  256, 1280, 1, 5120, 0);

    // ---------------- s3: T=64 I=144 O=20 C=80 Gs=64 Kpad=192 ----------------
    cvt_w<<<dim3(6, 1, 64), 256, 0, stream>>>(W3, wbt, 144, 20, 20, 192);
    gemm_small<32, 64><<<dim3(1, 32, 64), 256, 0, stream>>>(bufA, xg, wbt, b3, bufB,
                                                            64, 144, 20, 80, 64, 192, 1280);
    bn_stats_part<<<dim3(5, 16), 256, 0, stream>>>(bufB, sp, 1280, 1280);
    bn_scale16<<<5, 256, 0, stream>>>(sp, g3, bb3, ss, 1280);
    bn_tanh_head_vec<5><<<BDIM / 4, 256, 0, stream>>>(bufB, ss, hw3, hb3, out,
                                                      64, 320, 4, 1280, 256);

    // ---------------- s2: T=16 I=336 O=77 C=80 Gs=256 Kpad=384 ----------------
    cvt_w<<<dim3(12, 3, 16), 256, 0, stream>>>(W2, wbt, 336, 77, 77, 384);
    gemm_small<64, 64><<<dim3(2, 32, 16), 256, 0, stream>>>(bufB, xg, wbt, b2, bufC,
                                                            16, 336, 77, 80, 256, 384, 1232);
    bn_stats_part<<<dim3(5, 16), 256, 0, stream>>>(bufC, sp, 1232, 1232);
    bn_scale16<<<5, 256, 0, stream>>>(sp, g2, bb2, ss, 1232);
    // act2 -> Ain1 strided: col = (t/4)*1344 + (t%4)*77 + o
    bn_tanh_head<<<BDIM * 16 / 4, 256, 0, stream>>>(bufC, ss, hw2, hb2,
                                                    ain1, out, 16, 77, 1232, 5376, 4, 1344, 320, 1232);

    // ---------------- s1: T=4 I=1332 O=308 Kpad=1344 Npad=320 KS=2 ----------------
    cvt_w<<<dim3(42, 10, 4), 256, 0, stream>>>(W1, wbt, 1332, 308, 320, 1344);
    gemm_split<64><<<dim3(5, 16, 8), 256, 0, stream>>>(ain1, wbt, partial,
                                                       5376, 1344, 1344, 320, 2, 1280);
    reduce_bias_stats<<<dim3(20, 16), 256, 0, stream>>>(partial, b1, bufC, sp,
                                                        4, 308, 320, 2, 1232, 1232);
    bn_scale16<<<5, 256, 0, stream>>>(sp, g1, bb1, ss, 1232);
    // act1 -> Ain0 cols [0,1232): col = t*308 + o
    bn_tanh_head<<<BDIM * 4 / 4, 256, 0, stream>>>(bufC, ss, hw1, hb1,
                                                   ain0, out, 4, 308, 1232, 5376, 4, 0, 336, 1232);

    // ---------------- s0: T=1 I=5328 O=1229 Kpad=5376 Npad=1280 KS=4 ----------------
    cvt_w<<<dim3(168, 40, 1), 256, 0, stream>>>(W0, wbt, 5328, 1229, 1280, 5376);
    gemm_split<128><<<dim3(10, 16, 4), 256, 0, stream>>>(ain0, wbt, partial,
                                                         5376, 0, 5376, 1280, 4, 1280);
    reduce_bias_stats<<<dim3(20, 16), 256, 0, stream>>>(partial, b0_, bufC, sp,
                                                        1, 1229, 1280, 4, 1232, 1229);
    bn_scale16<<<5, 256, 0, stream>>>(sp, g0, bb0, ss, 1229);
    bn_tanh_head<<<BDIM / 4, 256, 0, stream>>>(bufC, ss, hw0, hb0,
                                               bufC, out, 1, 1229, 1232, 1232, 1, 0, 340, 1229);
}

// Round 7
// 465.460 us; speedup vs baseline: 1.0393x; 1.0393x over previous
//
#include <hip/hip_runtime.h>
#include <hip/hip_bf16.h>

// DCell forward, bf16-MFMA. Round-7 structure (20 dispatches):
//  1 pack_x        : x fp32 read ONCE -> bf16 into ain0 (col 1232+) and ain1
//  2 cvt_w_all     : W4..W1 -> bf16 WbT sub-regions (coexist in wbt)
//  3-5  s4: gemm_small(+fused col stats) -> bn_scaleN -> bn_tanh_head_vec
//  6-8  s3: same
//  9-11 s2: gemm_small(+stats) -> bn_scaleN -> bn_tanh_head (wave, -> ain1)
//  12 gemm_split<64> s1 (BK=32 double-buffered, 1 barrier/K-step)
//  13 cvt_w0 (overlaps s1 tail; wbt region free after s1 gemm)
//  14-16 s1: reduce_bias_stats -> bn_scaleN -> bn_tanh_head (-> ain0)
//  17 gemm_split<128> s0 (dbuf)
//  18-20 s0: reduce_bias_stats -> bn_scaleN -> bn_tanh_head (no act store)
// Stage cfg (T,I,O,C,Gs): s4(256,16,20,0,16) s3(64,144,20,80,64)
//  s2(16,336,77,80,256) s1(4,1332,308,308,1024) s0(1,5328,1229,1232,4096)

#define BDIM 2048
#define OUTW 341

typedef __attribute__((ext_vector_type(8))) short short8;
typedef __attribute__((ext_vector_type(4))) float float4v;

static __device__ __forceinline__ unsigned short f2bf(float f) {
    union { float f; unsigned u; } c{f};
    unsigned r = c.u + 0x7FFF + ((c.u >> 16) & 1);  // RNE
    return (unsigned short)(r >> 16);
}
static __device__ __forceinline__ float bf2f(unsigned short s) {
    union { unsigned u; float f; } c{(unsigned)s << 16};
    return c.f;
}

static __device__ __forceinline__ float fast_tanh(float x) {
    float ax = __builtin_fabsf(x);
    float e  = __builtin_amdgcn_exp2f(ax * 2.8853900817779268f);  // e^{2|x|}
    float r  = 1.f - 2.f * __builtin_amdgcn_rcpf(e + 1.f);
    return __builtin_copysignf(r, x);
}

// async global->LDS, 16B/lane: wave-uniform base + lane*16.
static __device__ __forceinline__ void stage16(const void* g, void* ldsBase, int lane) {
#if __has_builtin(__builtin_amdgcn_global_load_lds)
    __builtin_amdgcn_global_load_lds(
        (const __attribute__((address_space(1))) unsigned int*)(uintptr_t)g,
        (__attribute__((address_space(3))) unsigned int*)(unsigned int)(uintptr_t)ldsBase,
        16, 0, 0);
#else
    *(uint4*)((char*)ldsBase + lane * 16) = *(const uint4*)g;
#endif
}

// ---- fused x pack: read x once, write ain0 gene block + ain1 gene blocks + zero pads
__global__ __launch_bounds__(256) void pack_x(const float* __restrict__ x,
                                              unsigned short* __restrict__ ain0,
                                              unsigned short* __restrict__ ain1) {
    const int MAIN = BDIM * 512;          // 8-float units
    int i = blockIdx.x * 256 + threadIdx.x;
    if (i < MAIN) {
        int b = i >> 9, j = i & 511;
        const float* xp = x + (size_t)b * 4096 + j * 8;
        float4 lo = *(const float4*)xp, hi = *(const float4*)(xp + 4);
        union { unsigned short u[8]; uint4 v4; uint2 v2[2]; } t;
        t.u[0] = f2bf(lo.x); t.u[1] = f2bf(lo.y); t.u[2] = f2bf(lo.z); t.u[3] = f2bf(lo.w);
        t.u[4] = f2bf(hi.x); t.u[5] = f2bf(hi.y); t.u[6] = f2bf(hi.z); t.u[7] = f2bf(hi.w);
        *(uint4*)(ain0 + (size_t)b * 5376 + 1232 + j * 8) = t.v4;       // 16B aligned
        int gi = j * 8, tt = gi >> 10, u = gi & 1023;
        unsigned short* d1 = ain1 + (size_t)b * 5376 + tt * 1344 + 308 + u;  // 8B aligned
        *(uint2*)d1 = t.v2[0];
        *(uint2*)(d1 + 4) = t.v2[1];
        return;
    }
    int zi = i - MAIN;                    // zero pads, uint2 (4-short) units
    const int ZU = BDIM * 12;             // per-buffer zero units
    if (zi < ZU) {                        // ain0: cols [5328,5376)
        int b = zi / 12, u = zi % 12;
        *(uint2*)(ain0 + (size_t)b * 5376 + 5328 + u * 4) = make_uint2(0u, 0u);
    } else if (zi < 2 * ZU) {             // ain1: cols [t*1344+1332, +1344)
        zi -= ZU;
        int b = zi / 12, u = zi % 12, tt = u / 3, k = u % 3;
        *(uint2*)(ain1 + (size_t)b * 5376 + tt * 1344 + 1332 + k * 4) = make_uint2(0u, 0u);
    }
}

// ---- W[t][I][O] fp32 -> WbT[t][Npad][Kpad] bf16 core ----
static __device__ __forceinline__ void cvt_w_body(const float* Wt, unsigned short* dst,
                                                  int I, int O, int Npad, int Kpad,
                                                  int i0, int o0, int tid) {
    __shared__ unsigned short tile[32][33];
    const int c = tid & 31, r0 = tid >> 5;
    #pragma unroll
    for (int rr = 0; rr < 4; rr++) {
        int i = i0 + r0 + rr * 8, o = o0 + c;
        float v = (i < I && o < O) ? Wt[(size_t)i * O + o] : 0.f;
        tile[r0 + rr * 8][c] = f2bf(v);
    }
    __syncthreads();
    #pragma unroll
    for (int rr = 0; rr < 4; rr++) {
        int o = o0 + r0 + rr * 8, k = i0 + c;
        if (o < Npad) dst[(size_t)o * Kpad + k] = tile[c][r0 + rr * 8];
    }
}

// all of s4..s1 in one launch; flat grid with per-stage ranges
__global__ __launch_bounds__(256) void cvt_w_all(const float* __restrict__ W4,
                                                 const float* __restrict__ W3,
                                                 const float* __restrict__ W2,
                                                 const float* __restrict__ W1,
                                                 unsigned short* __restrict__ wbt) {
    int bid = blockIdx.x;
    const float* W; unsigned short* dst;
    int I, O, Npad, Kpad, gx, gy, local;
    if (bid < 256)       { W = W4; dst = wbt;           I = 16;   O = 20;  Npad = 20;  Kpad = 32;   gx = 1;  gy = 1;  local = bid; }
    else if (bid < 640)  { W = W3; dst = wbt + 163840;  I = 144;  O = 20;  Npad = 20;  Kpad = 192;  gx = 6;  gy = 1;  local = bid - 256; }
    else if (bid < 1216) { W = W2; dst = wbt + 409600;  I = 336;  O = 77;  Npad = 77;  Kpad = 384;  gx = 12; gy = 3;  local = bid - 640; }
    else                 { W = W1; dst = wbt + 882688;  I = 1332; O = 308; Npad = 320; Kpad = 1344; gx = 42; gy = 10; local = bid - 1216; }
    int per = gx * gy;
    int t = local / per, rem = local % per;
    int by = rem / gx, bx = rem % gx;
    cvt_w_body(W + (size_t)t * I * O, dst + (size_t)t * Npad * Kpad,
               I, O, Npad, Kpad, bx * 32, by * 32, threadIdx.x);
}

__global__ __launch_bounds__(256) void cvt_w(const float* __restrict__ W,
                                             unsigned short* __restrict__ WbT,
                                             int I, int O, int Npad, int Kpad) {
    cvt_w_body(W + (size_t)blockIdx.z * I * O, WbT + (size_t)blockIdx.z * Npad * Kpad,
               I, O, Npad, Kpad, blockIdx.x * 32, blockIdx.y * 32, threadIdx.x);
}

// ---- small-stage GEMM + fused column stats (chunk = blockIdx.y, 32 chunks of 64 rows)
template <int BN, int BK>
__global__ __launch_bounds__(256) void gemm_small(
    const unsigned short* __restrict__ actb,  // [B][T*C] bf16 (null if C==0)
    const unsigned short* __restrict__ xg,    // bf16 x copy, row stride 5376
    const unsigned short* __restrict__ WbT,   // [T][O][Kpad] bf16
    const float* __restrict__ bias,
    unsigned short* __restrict__ h,           // [B][hstride]
    float* __restrict__ sp,                   // [32][2*TO] col-sum partials
    int T, int I, int O, int C, int Gs, int Kpad, int hstride, int TO)
{
    const int t  = blockIdx.z;
    const int b0 = blockIdx.y * 64;
    const int o0 = blockIdx.x * BN;
    const int tid = threadIdx.x;
    const int lane = tid & 63;
    const int w = tid >> 6;
    const int l15 = lane & 15;
    const int quad = lane >> 4;

    constexpr int NF = BN / 32;
    const int wm = (w & 1) * 32;
    const int wn = (w >> 1) * (BN / 2);

    __shared__ __align__(16) unsigned short As[64][BK + 8];
    __shared__ __align__(16) unsigned short Bs[BN][BK + 8];
    __shared__ float ldsS[2][BN], ldsS2[2][BN];

    float4v acc[2][NF];
    #pragma unroll
    for (int a = 0; a < 2; a++)
        #pragma unroll
        for (int b = 0; b < NF; b++)
            acc[a][b] = (float4v){0.f, 0.f, 0.f, 0.f};

    constexpr int GR = BK / 8;
    constexpr int AG = 64 * GR;
    constexpr int BG = BN * GR;
    const size_t actRow = (size_t)T * C;

    for (int k0 = 0; k0 < Kpad; k0 += BK) {
        #pragma unroll
        for (int g = tid; g < AG; g += 256) {
            const int r = g / GR, c8 = g % GR;
            const int k = k0 + c8 * 8;
            const int b = b0 + r;
            uint4 v;
            if (k + 8 <= C) {
                v = *(const uint4*)(actb + (size_t)b * actRow + (size_t)t * C + k);
            } else if (k >= I) {
                v = make_uint4(0u, 0u, 0u, 0u);
            } else {
                v = *(const uint4*)(xg + (size_t)b * 5376 + (size_t)t * Gs + (k - C));
            }
            *(uint4*)&As[r][c8 * 8] = v;
        }
        #pragma unroll
        for (int g = tid; g < BG; g += 256) {
            const int n = g / GR, c8 = g % GR;
            const int o = o0 + n;
            uint4 v = make_uint4(0u, 0u, 0u, 0u);
            if (o < O)
                v = *(const uint4*)(WbT + ((size_t)t * O + o) * Kpad + k0 + c8 * 8);
            *(uint4*)&Bs[n][c8 * 8] = v;
        }
        __syncthreads();
        #pragma unroll
        for (int ks = 0; ks < BK / 32; ks++) {
            const int koff = ks * 32 + quad * 8;
            short8 a0 = *(const short8*)&As[wm + l15][koff];
            short8 a1 = *(const short8*)&As[wm + 16 + l15][koff];
            #pragma unroll
            for (int fn = 0; fn < NF; fn++) {
                short8 bf = *(const short8*)&Bs[wn + fn * 16 + l15][koff];
                acc[0][fn] = __builtin_amdgcn_mfma_f32_16x16x32_bf16(a0, bf, acc[0][fn], 0, 0, 0);
                acc[1][fn] = __builtin_amdgcn_mfma_f32_16x16x32_bf16(a1, bf, acc[1][fn], 0, 0, 0);
            }
        }
        __syncthreads();
    }

    // epilogue + per-thread column partial sums (fp32, pre-rounding)
    float csum[NF], csum2[NF];
    #pragma unroll
    for (int fn = 0; fn < NF; fn++) { csum[fn] = 0.f; csum2[fn] = 0.f; }
    #pragma unroll
    for (int fm = 0; fm < 2; fm++)
        #pragma unroll
        for (int fn = 0; fn < NF; fn++)
            #pragma unroll
            for (int r = 0; r < 4; r++) {
                int m = wm + fm * 16 + quad * 4 + r;
                int o = o0 + wn + fn * 16 + l15;
                if (o < O) {
                    float v = acc[fm][fn][r] + bias[t * O + o];
                    h[(size_t)(b0 + m) * hstride + (size_t)t * O + o] = f2bf(v);
                    csum[fn] += v; csum2[fn] += v * v;
                }
            }
    // reduce rows: quads within wave, then the 2 row-half waves via LDS
    #pragma unroll
    for (int fn = 0; fn < NF; fn++) {
        csum[fn]  += __shfl_xor(csum[fn], 16, 64);
        csum[fn]  += __shfl_xor(csum[fn], 32, 64);
        csum2[fn] += __shfl_xor(csum2[fn], 16, 64);
        csum2[fn] += __shfl_xor(csum2[fn], 32, 64);
    }
    if (quad == 0) {
        #pragma unroll
        for (int fn = 0; fn < NF; fn++) {
            ldsS[w & 1][wn + fn * 16 + l15]  = csum[fn];
            ldsS2[w & 1][wn + fn * 16 + l15] = csum2[fn];
        }
    }
    __syncthreads();
    if (tid < BN && o0 + tid < O) {
        int col = t * O + o0 + tid;
        size_t base = (size_t)blockIdx.y * 2 * TO;
        sp[base + col]      = ldsS[0][tid] + ldsS[1][tid];
        sp[base + TO + col] = ldsS2[0][tid] + ldsS2[1][tid];
    }
}

// ---- big-stage GEMM (s1/s0): 128-row tile, BK=32, DOUBLE-BUFFERED LDS ----
// One barrier per K-step: loads for step s+1 issue after the barrier and fly
// during compute(s). LDS slot = row*4+pos, pos = kg ^ ((row>>1)&3) (verified 0-conflict).
template <int BN>
__global__ __launch_bounds__(256) void gemm_split(
    const unsigned short* __restrict__ A,     // [2048][aStride] bf16 (zero-padded)
    const unsigned short* __restrict__ WbT,   // [T][Npad][Kpad] bf16 (zero-padded)
    float* __restrict__ partial,              // [KS][2048][TNpad]
    int aStride, int tStride, int Kpad, int Npad, int KS, int TNpad)
{
    const int tid = threadIdx.x;
    const int lane = tid & 63, w = tid >> 6;
    const int l15 = lane & 15, quad = lane >> 4;
    const int n0 = blockIdx.x * BN;
    const int b0 = blockIdx.y * 128;
    const int ksIdx = blockIdx.z % KS;
    const int t = blockIdx.z / KS;

    __shared__ __align__(16) unsigned short As[2][128 * 32];   // 2 x 8 KB
    __shared__ __align__(16) unsigned short Bs[2][BN * 32];    // 2 x 8/4 KB

    const int S = Kpad >> 5;
    const int qb = S / KS, rb = S % KS;
    const int beg = ksIdx * qb + (ksIdx < rb ? ksIdx : rb);
    const int cnt = qb + (ksIdx < rb ? 1 : 0);

    constexpr int NF = BN / 32;
    const int wm = (w & 1) * 64;
    const int wn = (w >> 1) * (BN / 2);

    float4v acc[4][NF];
    #pragma unroll
    for (int a = 0; a < 4; a++)
        #pragma unroll
        for (int b = 0; b < NF; b++)
            acc[a][b] = (float4v){0.f, 0.f, 0.f, 0.f};

    // A staging: 512 granule-slots, 2 calls/wave
    const unsigned short* aSrc[2];
    int aOff[2];
    #pragma unroll
    for (int j = 0; j < 2; j++) {
        int s = (w * 2 + j) * 64 + lane;
        int r = s >> 2, kg = (s & 3) ^ ((r >> 1) & 3);
        aSrc[j] = A + (size_t)(b0 + r) * aStride + (size_t)t * tStride + kg * 8;
        aOff[j] = (w * 2 + j) * 512;           // shorts
    }
    // B staging
    constexpr int BCALLS = (BN == 128) ? 2 : 1;
    const unsigned short* bSrc[BCALLS];
    int bOff[BCALLS];
    #pragma unroll
    for (int j = 0; j < BCALLS; j++) {
        int s = (w * BCALLS + j) * 64 + lane;
        int r = s >> 2, kg = (s & 3) ^ ((r >> 1) & 3);
        bSrc[j] = WbT + ((size_t)t * Npad + n0 + r) * Kpad + kg * 8;
        bOff[j] = (w * BCALLS + j) * 512;
    }

    // prologue: stage step 0 into buf 0
    {
        const int k0 = beg << 5;
        #pragma unroll
        for (int j = 0; j < 2; j++)      stage16(aSrc[j] + k0, &As[0][aOff[j]], lane);
        #pragma unroll
        for (int j = 0; j < BCALLS; j++) stage16(bSrc[j] + k0, &Bs[0][bOff[j]], lane);
    }

    for (int s = 0; s < cnt; s++) {
        const int cur = s & 1;
        __syncthreads();   // drains cur-buf loads (in flight since prev iter) + prev compute
        if (s + 1 < cnt) {
            const int k1 = (beg + s + 1) << 5;
            #pragma unroll
            for (int j = 0; j < 2; j++)      stage16(aSrc[j] + k1, &As[cur ^ 1][aOff[j]], lane);
            #pragma unroll
            for (int j = 0; j < BCALLS; j++) stage16(bSrc[j] + k1, &Bs[cur ^ 1][bOff[j]], lane);
        }
        short8 af[4];
        #pragma unroll
        for (int fm = 0; fm < 4; fm++) {
            int m = wm + fm * 16 + l15;
            int pos = quad ^ ((m >> 1) & 3);
            af[fm] = *(const short8*)&As[cur][(m * 4 + pos) * 8];
        }
        short8 bfr[NF];
        #pragma unroll
        for (int fn = 0; fn < NF; fn++) {
            int n = wn + fn * 16 + l15;
            int pos = quad ^ ((n >> 1) & 3);
            bfr[fn] = *(const short8*)&Bs[cur][(n * 4 + pos) * 8];
        }
        #pragma unroll
        for (int fm = 0; fm < 4; fm++)
            #pragma unroll
            for (int fn = 0; fn < NF; fn++)
                acc[fm][fn] = __builtin_amdgcn_mfma_f32_16x16x32_bf16(af[fm], bfr[fn], acc[fm][fn], 0, 0, 0);
    }

    const size_t pBase = ((size_t)ksIdx * BDIM + b0) * TNpad + (size_t)t * Npad + n0;
    #pragma unroll
    for (int fm = 0; fm < 4; fm++)
        #pragma unroll
        for (int r = 0; r < 4; r++) {
            const int m = wm + fm * 16 + quad * 4 + r;
            float* prow = partial + pBase + (size_t)m * TNpad + wn;
            #pragma unroll
            for (int fn = 0; fn < NF; fn++)
                prow[fn * 16 + l15] = acc[fm][fn][r];
        }
}

// ---- fused split-K reduce + bias + bf16 h store + per-chunk stats partials ----
__global__ __launch_bounds__(256) void reduce_bias_stats(
    const float* __restrict__ partial, const float* __restrict__ bias,
    unsigned short* __restrict__ h, float* __restrict__ sp,
    int T, int O, int Npad, int KS, int hstride, int TO)
{
    __shared__ float redS[4][64], redS2[4][64];
    const int colL = threadIdx.x & 63;
    const int cr = threadIdx.x >> 6;
    const int col = blockIdx.x * 64 + colL;
    const int chunk = blockIdx.y;
    float s = 0.f, s2 = 0.f;
    if (col < TO) {
        int t = col / O, o = col - t * O;
        const size_t TNpad = (size_t)T * Npad;
        const size_t pcol = (size_t)t * Npad + o;
        const float bv = bias[col];
        const int row0 = chunk * 128 + cr * 32;
        for (int r = 0; r < 32; r++) {
            const int row = row0 + r;
            const float* p = partial + (size_t)row * TNpad + pcol;
            float v = bv;
            for (int ks = 0; ks < KS; ks++) v += p[(size_t)ks * BDIM * TNpad];
            h[(size_t)row * hstride + col] = f2bf(v);
            s += v; s2 += v * v;
        }
    }
    redS[cr][colL] = s; redS2[cr][colL] = s2;
    __syncthreads();
    if (cr == 0 && col < TO) {
        float ts  = redS[0][colL] + redS[1][colL] + redS[2][colL] + redS[3][colL];
        float ts2 = redS2[0][colL] + redS2[1][colL] + redS2[2][colL] + redS2[3][colL];
        sp[(size_t)chunk * 2 * TO + col] = ts;
        sp[(size_t)chunk * 2 * TO + TO + col] = ts2;
    }
}

// ---- fold NC chunk partials -> per-col scale/shift ----
__global__ __launch_bounds__(256) void bn_scaleN(const float* __restrict__ sp,
                                                 const float* __restrict__ g,
                                                 const float* __restrict__ bb,
                                                 float* __restrict__ ss, int TO, int NC) {
    int col = blockIdx.x * 256 + threadIdx.x;
    if (col >= TO) return;
    float s = 0.f, s2 = 0.f;
    for (int c = 0; c < NC; c++) {
        s  += sp[(size_t)c * 2 * TO + col];
        s2 += sp[(size_t)c * 2 * TO + TO + col];
    }
    float mu = s * (1.f / BDIM);
    float var = s2 * (1.f / BDIM) - mu * mu;  // biased, matches jnp.var
    float scale = rsqrtf(var + 1e-5f) * g[col];
    ss[col] = scale;
    ss[TO + col] = bb[col] - mu * scale;
}

// ---- vectorized BN+tanh+head for O=20 in-place stages (s4/s3) ----
template <int GPT>
__global__ __launch_bounds__(256) void bn_tanh_head_vec(
    unsigned short* hact, const float* __restrict__ ss,
    const float* __restrict__ hw, const float* __restrict__ hb,
    float* __restrict__ out,
    int T, int rowGran, int RPB, int hstride, int head_off)
{
    __shared__ float headAcc[256];
    const int tid = threadIdx.x;
    headAcc[tid] = 0.f;
    __syncthreads();
    const int b0 = blockIdx.x * RPB;

    uint2 hv[GPT];
    #pragma unroll
    for (int j = 0; j < GPT; j++) {
        int G = tid + j * 256;
        int r = G / rowGran, gg = G % rowGran;
        hv[j] = *(const uint2*)(hact + (size_t)(b0 + r) * hstride + gg * 4);
    }
    #pragma unroll
    for (int j = 0; j < GPT; j++) {
        int G = tid + j * 256;
        int r = G / rowGran, gg = G % rowGran;
        int c = gg * 4;
        float4 sc = *(const float4*)(ss + c);
        float4 sh = *(const float4*)(ss + hstride + c);
        float4 w4 = *(const float4*)(hw + c);
        union { unsigned short u[4]; uint2 v; } iv, ov;
        iv.v = hv[j];
        float a0 = fast_tanh(bf2f(iv.u[0]) * sc.x + sh.x);
        float a1 = fast_tanh(bf2f(iv.u[1]) * sc.y + sh.y);
        float a2 = fast_tanh(bf2f(iv.u[2]) * sc.z + sh.z);
        float a3 = fast_tanh(bf2f(iv.u[3]) * sc.w + sh.w);
        ov.u[0] = f2bf(a0); ov.u[1] = f2bf(a1); ov.u[2] = f2bf(a2); ov.u[3] = f2bf(a3);
        *(uint2*)(hact + (size_t)(b0 + r) * hstride + c) = ov.v;
        float partial = a0 * w4.x + a1 * w4.y + a2 * w4.z + a3 * w4.w;
        int t = gg / 5;
        atomicAdd(&headAcc[r * T + t], partial);
    }
    __syncthreads();
    if (tid < RPB * T) {
        int r = tid / T, t = tid % T;
        out[(size_t)(b0 + r) * OUTW + head_off + t] = headAcc[tid] + hb[t];
    }
}

// ---- BN + tanh + strided act store + head — WAVE variant ----
__global__ __launch_bounds__(256) void bn_tanh_head(
    const unsigned short* __restrict__ h, const float* __restrict__ ss,
    const float* __restrict__ hw, const float* __restrict__ hb,
    unsigned short* __restrict__ actOut, float* __restrict__ out,
    int T, int O, int hstride, int aRow, int GT, int GS, int head_off, int TO)
{
    int wid  = (blockIdx.x * 256 + threadIdx.x) >> 6;
    int lane = threadIdx.x & 63;
    int b = wid / T;
    int t = wid % T;
    const size_t hbase = (size_t)b * hstride + (size_t)t * O;
    const size_t abase = (size_t)b * aRow + (size_t)(t / GT) * GS + (size_t)(t % GT) * O;
    float hsum = 0.f;
    for (int o = lane; o < O; o += 64) {
        int col = t * O + o;
        float a = fast_tanh(bf2f(h[hbase + o]) * ss[col] + ss[TO + col]);
        if (actOut) actOut[abase + o] = f2bf(a);
        hsum += a * hw[col];
    }
    #pragma unroll
    for (int off = 32; off > 0; off >>= 1) hsum += __shfl_down(hsum, off, 64);
    if (lane == 0) out[(size_t)b * OUTW + head_off + t] = hsum + hb[t];
}

extern "C" void kernel_launch(void* const* d_in, const int* in_sizes, int n_in,
                              void* d_out, int out_size, void* d_ws, size_t ws_size,
                              hipStream_t stream)
{
    const float* x = (const float*)d_in[0];
    float* out = (float*)d_out;
    char* ws = (char*)d_ws;

    // ws layout (bytes)
    unsigned short* wbt  = (unsigned short*)(ws);              // 13,762,560
    unsigned short* ain0 = (unsigned short*)(ws + 13762560);   // 22,020,096 (2048x5376)
    unsigned short* bufA = (unsigned short*)(ws + 35782656);   // 20,971,520
    unsigned short* bufB = (unsigned short*)(ws + 56754176);   //  5,242,880
    unsigned short* ain1 = (unsigned short*)(ws + 61997056);   // 22,020,096
    unsigned short* bufC = (unsigned short*)(ws + 84017152);   //  5,046,272
    float*          ss   = (float*)(ws + 89063424);            //     40,960
    float*          sp0  = (float*)(ws + 89104384);            //    157,312 (16x2x1229)
    // overlays (all verified dead at use time):
    float* partial = (float*)(ws + 35782656);   // s1: 21 MB (=bufA), s0: 41.9 MB (bufA..ain1 head)
    float* sp4 = (float*)bufC;                  // 32x2x5120x4 = 1.31 MB (bufC free pre-s2)
    float* sp3 = (float*)bufC;                  // 0.33 MB
    float* sp2 = (float*)bufA;                  // 0.32 MB (act4 dead after s3 gemm)
    float* sp1 = (float*)bufB;                  // 0.32 MB (act3 dead after s2 gemm)
    unsigned short* xg = ain0 + 1232;           // full bf16 x copy, row stride 5376

    const float* W4 = (const float*)d_in[1];  const float* b4 = (const float*)d_in[2];
    const float* g4 = (const float*)d_in[3];  const float* bb4 = (const float*)d_in[4];
    const float* hw4 = (const float*)d_in[5]; const float* hb4 = (const float*)d_in[6];
    const float* W3 = (const float*)d_in[7];  const float* b3 = (const float*)d_in[8];
    const float* g3 = (const float*)d_in[9];  const float* bb3 = (const float*)d_in[10];
    const float* hw3 = (const float*)d_in[11]; const float* hb3 = (const float*)d_in[12];
    const float* W2 = (const float*)d_in[13]; const float* b2 = (const float*)d_in[14];
    const float* g2 = (const float*)d_in[15]; const float* bb2 = (const float*)d_in[16];
    const float* hw2 = (const float*)d_in[17]; const float* hb2 = (const float*)d_in[18];
    const float* W1 = (const float*)d_in[19]; const float* b1 = (const float*)d_in[20];
    const float* g1 = (const float*)d_in[21]; const float* bb1 = (const float*)d_in[22];
    const float* hw1 = (const float*)d_in[23]; const float* hb1 = (const float*)d_in[24];
    const float* W0 = (const float*)d_in[25]; const float* b0_ = (const float*)d_in[26];
    const float* g0 = (const float*)d_in[27]; const float* bb0 = (const float*)d_in[28];
    const float* hw0 = (const float*)d_in[29]; const float* hb0 = (const float*)d_in[30];

    // 1-2: packs + weight conversions (s4..s1)
    pack_x<<<(BDIM * 512 + BDIM * 24 + 255) / 256, 256, 0, stream>>>(x, ain0, ain1);
    cvt_w_all<<<2896, 256, 0, stream>>>(W4, W3, W2, W1, wbt);

    // s4: T=256 I=16 O=20 Kpad=32, WbT @0
    gemm_small<32, 32><<<dim3(1, 32, 256), 256, 0, stream>>>(nullptr, xg, wbt, b4, bufA,
                                                             sp4, 256, 16, 20, 0, 16, 32, 5120, 5120);
    bn_scaleN<<<20, 256, 0, stream>>>(sp4, g4, bb4, ss, 5120, 32);
    bn_tanh_head_vec<5><<<BDIM, 256, 0, stream>>>(bufA, ss, hw4, hb4, out, 256, 1280, 1, 5120, 0);

    // s3: T=64 I=144 O=20 Kpad=192, WbT @163840
    gemm_small<32, 64><<<dim3(1, 32, 64), 256, 0, stream>>>(bufA, xg, wbt + 163840, b3, bufB,
                                                            sp3, 64, 144, 20, 80, 64, 192, 1280, 1280);
    bn_scaleN<<<5, 256, 0, stream>>>(sp3, g3, bb3, ss, 1280, 32);
    bn_tanh_head_vec<5><<<BDIM / 4, 256, 0, stream>>>(bufB, ss, hw3, hb3, out, 64, 320, 4, 1280, 256);

    // s2: T=16 I=336 O=77 Kpad=384, WbT @409600
    gemm_small<64, 64><<<dim3(2, 32, 16), 256, 0, stream>>>(bufB, xg, wbt + 409600, b2, bufC,
                                                            sp2, 16, 336, 77, 80, 256, 384, 1232, 1232);
    bn_scaleN<<<5, 256, 0, stream>>>(sp2, g2, bb2, ss, 1232, 32);
    bn_tanh_head<<<BDIM * 16 / 4, 256, 0, stream>>>(bufC, ss, hw2, hb2,
                                                    ain1, out, 16, 77, 1232, 5376, 4, 1344, 320, 1232);

    // s1: T=4 I=1332 O=308 Kpad=1344 Npad=320 KS=2, WbT @882688
    gemm_split<64><<<dim3(5, 16, 8), 256, 0, stream>>>(ain1, wbt + 882688, partial,
                                                       5376, 1344, 1344, 320, 2, 1280);
    cvt_w<<<dim3(168, 40, 1), 256, 0, stream>>>(W0, wbt, 5328, 1229, 1280, 5376);  // overlaps s1 tail
    reduce_bias_stats<<<dim3(20, 16), 256, 0, stream>>>(partial, b1, bufC, sp1,
                                                        4, 308, 320, 2, 1232, 1232);
    bn_scaleN<<<5, 256, 0, stream>>>(sp1, g1, bb1, ss, 1232, 16);
    bn_tanh_head<<<BDIM * 4 / 4, 256, 0, stream>>>(bufC, ss, hw1, hb1,
                                                   ain0, out, 4, 308, 1232, 5376, 4, 0, 336, 1232);

    // s0: T=1 I=5328 O=1229 Kpad=5376 Npad=1280 KS=4
    gemm_split<128><<<dim3(10, 16, 4), 256, 0, stream>>>(ain0, wbt, partial,
                                                         5376, 0, 5376, 1280, 4, 1280);
    reduce_bias_stats<<<dim3(20, 16), 256, 0, stream>>>(partial, b0_, bufC, sp0,
                                                        1, 1229, 1280, 4, 1232, 1229);
    bn_scaleN<<<5, 256, 0, stream>>>(sp0, g0, bb0, ss, 1229, 16);
    bn_tanh_head<<<BDIM / 4, 256, 0, stream>>>(bufC, ss, hw0, hb0,
                                               nullptr, out, 1, 1229, 1232, 1232, 1, 0, 340, 1229);
}

// Round 9
// 450.295 us; speedup vs baseline: 1.0743x; 1.0337x over previous
//
#include <hip/hip_runtime.h>
#include <hip/hip_bf16.h>

// DCell forward, bf16-MFMA. Round-8 (resubmit; prior bench was an infra failure):
// XCD-aware swizzle in gemm_split.
//  1 pack_x        : x fp32 read ONCE -> bf16 into ain0 (col 1232+) and ain1
//  2 cvt_w_all     : W4..W1 -> bf16 WbT sub-regions (coexist in wbt)
//  3-5  s4: gemm_small(+fused col stats) -> bn_scaleN -> bn_tanh_head_vec
//  6-8  s3: same
//  9-11 s2: gemm_small(+stats) -> bn_scaleN -> bn_tanh_head (wave, -> ain1)
//  12 gemm_split<64> s1 (BK=32 dbuf, 1 barrier/K-step, 1D swizzled grid)
//  13 cvt_w0 (overlaps s1 tail)
//  14-16 s1: reduce_bias_stats -> bn_scaleN -> bn_tanh_head (-> ain0)
//  17 gemm_split<128> s0 (dbuf, swizzled)
//  18-20 s0: reduce_bias_stats -> bn_scaleN -> bn_tanh_head (no act store)
// Swizzle: id = c + 8*(q*nTiles + n), group = q*8+c = (b-tile*T*KS + t*KS + ks).
// All nTiles blocks sharing an A-slab have id ≡ c (mod 8) -> same XCD -> one
// L2 fill per slab (round-7 FETCH was 3.5x unique bytes from cross-XCD fills).
// Stage cfg (T,I,O,C,Gs): s4(256,16,20,0,16) s3(64,144,20,80,64)
//  s2(16,336,77,80,256) s1(4,1332,308,308,1024) s0(1,5328,1229,1232,4096)

#define BDIM 2048
#define OUTW 341

typedef __attribute__((ext_vector_type(8))) short short8;
typedef __attribute__((ext_vector_type(4))) float float4v;

static __device__ __forceinline__ unsigned short f2bf(float f) {
    union { float f; unsigned u; } c{f};
    unsigned r = c.u + 0x7FFF + ((c.u >> 16) & 1);  // RNE
    return (unsigned short)(r >> 16);
}
static __device__ __forceinline__ float bf2f(unsigned short s) {
    union { unsigned u; float f; } c{(unsigned)s << 16};
    return c.f;
}

static __device__ __forceinline__ float fast_tanh(float x) {
    float ax = __builtin_fabsf(x);
    float e  = __builtin_amdgcn_exp2f(ax * 2.8853900817779268f);  // e^{2|x|}
    float r  = 1.f - 2.f * __builtin_amdgcn_rcpf(e + 1.f);
    return __builtin_copysignf(r, x);
}

// async global->LDS, 16B/lane: wave-uniform base + lane*16.
static __device__ __forceinline__ void stage16(const void* g, void* ldsBase, int lane) {
#if __has_builtin(__builtin_amdgcn_global_load_lds)
    __builtin_amdgcn_global_load_lds(
        (const __attribute__((address_space(1))) unsigned int*)(uintptr_t)g,
        (__attribute__((address_space(3))) unsigned int*)(unsigned int)(uintptr_t)ldsBase,
        16, 0, 0);
#else
    *(uint4*)((char*)ldsBase + lane * 16) = *(const uint4*)g;
#endif
}

// ---- fused x pack: read x once, write ain0 gene block + ain1 gene blocks + zero pads
__global__ __launch_bounds__(256) void pack_x(const float* __restrict__ x,
                                              unsigned short* __restrict__ ain0,
                                              unsigned short* __restrict__ ain1) {
    const int MAIN = BDIM * 512;          // 8-float units
    int i = blockIdx.x * 256 + threadIdx.x;
    if (i < MAIN) {
        int b = i >> 9, j = i & 511;
        const float* xp = x + (size_t)b * 4096 + j * 8;
        float4 lo = *(const float4*)xp, hi = *(const float4*)(xp + 4);
        union { unsigned short u[8]; uint4 v4; uint2 v2[2]; } t;
        t.u[0] = f2bf(lo.x); t.u[1] = f2bf(lo.y); t.u[2] = f2bf(lo.z); t.u[3] = f2bf(lo.w);
        t.u[4] = f2bf(hi.x); t.u[5] = f2bf(hi.y); t.u[6] = f2bf(hi.z); t.u[7] = f2bf(hi.w);
        *(uint4*)(ain0 + (size_t)b * 5376 + 1232 + j * 8) = t.v4;       // 16B aligned
        int gi = j * 8, tt = gi >> 10, u = gi & 1023;
        unsigned short* d1 = ain1 + (size_t)b * 5376 + tt * 1344 + 308 + u;  // 8B aligned
        *(uint2*)d1 = t.v2[0];
        *(uint2*)(d1 + 4) = t.v2[1];
        return;
    }
    int zi = i - MAIN;                    // zero pads, uint2 (4-short) units
    const int ZU = BDIM * 12;             // per-buffer zero units
    if (zi < ZU) {                        // ain0: cols [5328,5376)
        int b = zi / 12, u = zi % 12;
        *(uint2*)(ain0 + (size_t)b * 5376 + 5328 + u * 4) = make_uint2(0u, 0u);
    } else if (zi < 2 * ZU) {             // ain1: cols [t*1344+1332, +1344)
        zi -= ZU;
        int b = zi / 12, u = zi % 12, tt = u / 3, k = u % 3;
        *(uint2*)(ain1 + (size_t)b * 5376 + tt * 1344 + 1332 + k * 4) = make_uint2(0u, 0u);
    }
}

// ---- W[t][I][O] fp32 -> WbT[t][Npad][Kpad] bf16 core ----
static __device__ __forceinline__ void cvt_w_body(const float* Wt, unsigned short* dst,
                                                  int I, int O, int Npad, int Kpad,
                                                  int i0, int o0, int tid) {
    __shared__ unsigned short tile[32][33];
    const int c = tid & 31, r0 = tid >> 5;
    #pragma unroll
    for (int rr = 0; rr < 4; rr++) {
        int i = i0 + r0 + rr * 8, o = o0 + c;
        float v = (i < I && o < O) ? Wt[(size_t)i * O + o] : 0.f;
        tile[r0 + rr * 8][c] = f2bf(v);
    }
    __syncthreads();
    #pragma unroll
    for (int rr = 0; rr < 4; rr++) {
        int o = o0 + r0 + rr * 8, k = i0 + c;
        if (o < Npad) dst[(size_t)o * Kpad + k] = tile[c][r0 + rr * 8];
    }
}

// all of s4..s1 in one launch; flat grid with per-stage ranges
__global__ __launch_bounds__(256) void cvt_w_all(const float* __restrict__ W4,
                                                 const float* __restrict__ W3,
                                                 const float* __restrict__ W2,
                                                 const float* __restrict__ W1,
                                                 unsigned short* __restrict__ wbt) {
    int bid = blockIdx.x;
    const float* W; unsigned short* dst;
    int I, O, Npad, Kpad, gx, gy, local;
    if (bid < 256)       { W = W4; dst = wbt;           I = 16;   O = 20;  Npad = 20;  Kpad = 32;   gx = 1;  gy = 1;  local = bid; }
    else if (bid < 640)  { W = W3; dst = wbt + 163840;  I = 144;  O = 20;  Npad = 20;  Kpad = 192;  gx = 6;  gy = 1;  local = bid - 256; }
    else if (bid < 1216) { W = W2; dst = wbt + 409600;  I = 336;  O = 77;  Npad = 77;  Kpad = 384;  gx = 12; gy = 3;  local = bid - 640; }
    else                 { W = W1; dst = wbt + 882688;  I = 1332; O = 308; Npad = 320; Kpad = 1344; gx = 42; gy = 10; local = bid - 1216; }
    int per = gx * gy;
    int t = local / per, rem = local % per;
    int by = rem / gx, bx = rem % gx;
    cvt_w_body(W + (size_t)t * I * O, dst + (size_t)t * Npad * Kpad,
               I, O, Npad, Kpad, bx * 32, by * 32, threadIdx.x);
}

__global__ __launch_bounds__(256) void cvt_w(const float* __restrict__ W,
                                             unsigned short* __restrict__ WbT,
                                             int I, int O, int Npad, int Kpad) {
    cvt_w_body(W + (size_t)blockIdx.z * I * O, WbT + (size_t)blockIdx.z * Npad * Kpad,
               I, O, Npad, Kpad, blockIdx.x * 32, blockIdx.y * 32, threadIdx.x);
}

// ---- small-stage GEMM + fused column stats (chunk = blockIdx.y, 32 chunks of 64 rows)
template <int BN, int BK>
__global__ __launch_bounds__(256) void gemm_small(
    const unsigned short* __restrict__ actb,  // [B][T*C] bf16 (null if C==0)
    const unsigned short* __restrict__ xg,    // bf16 x copy, row stride 5376
    const unsigned short* __restrict__ WbT,   // [T][O][Kpad] bf16
    const float* __restrict__ bias,
    unsigned short* __restrict__ h,           // [B][hstride]
    float* __restrict__ sp,                   // [32][2*TO] col-sum partials
    int T, int I, int O, int C, int Gs, int Kpad, int hstride, int TO)
{
    const int t  = blockIdx.z;
    const int b0 = blockIdx.y * 64;
    const int o0 = blockIdx.x * BN;
    const int tid = threadIdx.x;
    const int lane = tid & 63;
    const int w = tid >> 6;
    const int l15 = lane & 15;
    const int quad = lane >> 4;

    constexpr int NF = BN / 32;
    const int wm = (w & 1) * 32;
    const int wn = (w >> 1) * (BN / 2);

    __shared__ __align__(16) unsigned short As[64][BK + 8];
    __shared__ __align__(16) unsigned short Bs[BN][BK + 8];
    __shared__ float ldsS[2][BN], ldsS2[2][BN];

    float4v acc[2][NF];
    #pragma unroll
    for (int a = 0; a < 2; a++)
        #pragma unroll
        for (int b = 0; b < NF; b++)
            acc[a][b] = (float4v){0.f, 0.f, 0.f, 0.f};

    constexpr int GR = BK / 8;
    constexpr int AG = 64 * GR;
    constexpr int BG = BN * GR;
    const size_t actRow = (size_t)T * C;

    for (int k0 = 0; k0 < Kpad; k0 += BK) {
        #pragma unroll
        for (int g = tid; g < AG; g += 256) {
            const int r = g / GR, c8 = g % GR;
            const int k = k0 + c8 * 8;
            const int b = b0 + r;
            uint4 v;
            if (k + 8 <= C) {
                v = *(const uint4*)(actb + (size_t)b * actRow + (size_t)t * C + k);
            } else if (k >= I) {
                v = make_uint4(0u, 0u, 0u, 0u);
            } else {
                v = *(const uint4*)(xg + (size_t)b * 5376 + (size_t)t * Gs + (k - C));
            }
            *(uint4*)&As[r][c8 * 8] = v;
        }
        #pragma unroll
        for (int g = tid; g < BG; g += 256) {
            const int n = g / GR, c8 = g % GR;
            const int o = o0 + n;
            uint4 v = make_uint4(0u, 0u, 0u, 0u);
            if (o < O)
                v = *(const uint4*)(WbT + ((size_t)t * O + o) * Kpad + k0 + c8 * 8);
            *(uint4*)&Bs[n][c8 * 8] = v;
        }
        __syncthreads();
        #pragma unroll
        for (int ks = 0; ks < BK / 32; ks++) {
            const int koff = ks * 32 + quad * 8;
            short8 a0 = *(const short8*)&As[wm + l15][koff];
            short8 a1 = *(const short8*)&As[wm + 16 + l15][koff];
            #pragma unroll
            for (int fn = 0; fn < NF; fn++) {
                short8 bf = *(const short8*)&Bs[wn + fn * 16 + l15][koff];
                acc[0][fn] = __builtin_amdgcn_mfma_f32_16x16x32_bf16(a0, bf, acc[0][fn], 0, 0, 0);
                acc[1][fn] = __builtin_amdgcn_mfma_f32_16x16x32_bf16(a1, bf, acc[1][fn], 0, 0, 0);
            }
        }
        __syncthreads();
    }

    // epilogue + per-thread column partial sums (fp32, pre-rounding)
    float csum[NF], csum2[NF];
    #pragma unroll
    for (int fn = 0; fn < NF; fn++) { csum[fn] = 0.f; csum2[fn] = 0.f; }
    #pragma unroll
    for (int fm = 0; fm < 2; fm++)
        #pragma unroll
        for (int fn = 0; fn < NF; fn++)
            #pragma unroll
            for (int r = 0; r < 4; r++) {
                int m = wm + fm * 16 + quad * 4 + r;
                int o = o0 + wn + fn * 16 + l15;
                if (o < O) {
                    float v = acc[fm][fn][r] + bias[t * O + o];
                    h[(size_t)(b0 + m) * hstride + (size_t)t * O + o] = f2bf(v);
                    csum[fn] += v; csum2[fn] += v * v;
                }
            }
    #pragma unroll
    for (int fn = 0; fn < NF; fn++) {
        csum[fn]  += __shfl_xor(csum[fn], 16, 64);
        csum[fn]  += __shfl_xor(csum[fn], 32, 64);
        csum2[fn] += __shfl_xor(csum2[fn], 16, 64);
        csum2[fn] += __shfl_xor(csum2[fn], 32, 64);
    }
    if (quad == 0) {
        #pragma unroll
        for (int fn = 0; fn < NF; fn++) {
            ldsS[w & 1][wn + fn * 16 + l15]  = csum[fn];
            ldsS2[w & 1][wn + fn * 16 + l15] = csum2[fn];
        }
    }
    __syncthreads();
    if (tid < BN && o0 + tid < O) {
        int col = t * O + o0 + tid;
        size_t base = (size_t)blockIdx.y * 2 * TO;
        sp[base + col]      = ldsS[0][tid] + ldsS[1][tid];
        sp[base + TO + col] = ldsS2[0][tid] + ldsS2[1][tid];
    }
}

// ---- big-stage GEMM (s1/s0): 128-row tile, BK=32, dbuf LDS, XCD-swizzled 1D grid
// id = c + 8*(q*nTiles + n); group = q*8+c = b*TKS + t*KS + ks. Same-A blocks
// (all n, fixed group) share XCD c. LDS slot = row*4+pos, pos = kg ^ ((row>>1)&3).
template <int BN>
__global__ __launch_bounds__(256) void gemm_split(
    const unsigned short* __restrict__ A,     // [2048][aStride] bf16 (zero-padded)
    const unsigned short* __restrict__ WbT,   // [T][Npad][Kpad] bf16 (zero-padded)
    float* __restrict__ partial,              // [KS][2048][TNpad]
    int aStride, int tStride, int Kpad, int Npad, int KS, int TNpad,
    int nTiles, int TKS)
{
    const int tid = threadIdx.x;
    const int lane = tid & 63, w = tid >> 6;
    const int l15 = lane & 15, quad = lane >> 4;

    // swizzled decode
    const int id = blockIdx.x;
    const int c = id & 7;
    const int tmp = id >> 3;
    const int n = tmp % nTiles;
    const int q = tmp / nTiles;
    const int group = q * 8 + c;
    const int b0 = (group / TKS) * 128;
    const int rem = group % TKS;
    const int t = rem / KS;
    const int ksIdx = rem - t * KS;
    const int n0 = n * BN;

    __shared__ __align__(16) unsigned short As[2][128 * 32];   // 2 x 8 KB
    __shared__ __align__(16) unsigned short Bs[2][BN * 32];    // 2 x 8/4 KB

    const int S = Kpad >> 5;
    const int qb = S / KS, rb = S % KS;
    const int beg = ksIdx * qb + (ksIdx < rb ? ksIdx : rb);
    const int cnt = qb + (ksIdx < rb ? 1 : 0);

    constexpr int NF = BN / 32;
    const int wm = (w & 1) * 64;
    const int wn = (w >> 1) * (BN / 2);

    float4v acc[4][NF];
    #pragma unroll
    for (int a = 0; a < 4; a++)
        #pragma unroll
        for (int b = 0; b < NF; b++)
            acc[a][b] = (float4v){0.f, 0.f, 0.f, 0.f};

    // A staging: 512 granule-slots, 2 calls/wave
    const unsigned short* aSrc[2];
    int aOff[2];
    #pragma unroll
    for (int j = 0; j < 2; j++) {
        int s = (w * 2 + j) * 64 + lane;
        int r = s >> 2, kg = (s & 3) ^ ((r >> 1) & 3);
        aSrc[j] = A + (size_t)(b0 + r) * aStride + (size_t)t * tStride + kg * 8;
        aOff[j] = (w * 2 + j) * 512;           // shorts
    }
    // B staging
    constexpr int BCALLS = (BN == 128) ? 2 : 1;
    const unsigned short* bSrc[BCALLS];
    int bOff[BCALLS];
    #pragma unroll
    for (int j = 0; j < BCALLS; j++) {
        int s = (w * BCALLS + j) * 64 + lane;
        int r = s >> 2, kg = (s & 3) ^ ((r >> 1) & 3);
        bSrc[j] = WbT + ((size_t)t * Npad + n0 + r) * Kpad + kg * 8;
        bOff[j] = (w * BCALLS + j) * 512;
    }

    // prologue: stage step 0 into buf 0
    {
        const int k0 = beg << 5;
        #pragma unroll
        for (int j = 0; j < 2; j++)      stage16(aSrc[j] + k0, &As[0][aOff[j]], lane);
        #pragma unroll
        for (int j = 0; j < BCALLS; j++) stage16(bSrc[j] + k0, &Bs[0][bOff[j]], lane);
    }

    for (int s = 0; s < cnt; s++) {
        const int cur = s & 1;
        __syncthreads();   // drains cur-buf loads (in flight since prev iter) + prev compute
        if (s + 1 < cnt) {
            const int k1 = (beg + s + 1) << 5;
            #pragma unroll
            for (int j = 0; j < 2; j++)      stage16(aSrc[j] + k1, &As[cur ^ 1][aOff[j]], lane);
            #pragma unroll
            for (int j = 0; j < BCALLS; j++) stage16(bSrc[j] + k1, &Bs[cur ^ 1][bOff[j]], lane);
        }
        short8 af[4];
        #pragma unroll
        for (int fm = 0; fm < 4; fm++) {
            int m = wm + fm * 16 + l15;
            int pos = quad ^ ((m >> 1) & 3);
            af[fm] = *(const short8*)&As[cur][(m * 4 + pos) * 8];
        }
        short8 bfr[NF];
        #pragma unroll
        for (int fn = 0; fn < NF; fn++) {
            int nn = wn + fn * 16 + l15;
            int pos = quad ^ ((nn >> 1) & 3);
            bfr[fn] = *(const short8*)&Bs[cur][(nn * 4 + pos) * 8];
        }
        #pragma unroll
        for (int fm = 0; fm < 4; fm++)
            #pragma unroll
            for (int fn = 0; fn < NF; fn++)
                acc[fm][fn] = __builtin_amdgcn_mfma_f32_16x16x32_bf16(af[fm], bfr[fn], acc[fm][fn], 0, 0, 0);
    }

    const size_t pBase = ((size_t)ksIdx * BDIM + b0) * TNpad + (size_t)t * Npad + n0;
    #pragma unroll
    for (int fm = 0; fm < 4; fm++)
        #pragma unroll
        for (int r = 0; r < 4; r++) {
            const int m = wm + fm * 16 + quad * 4 + r;
            float* prow = partial + pBase + (size_t)m * TNpad + wn;
            #pragma unroll
            for (int fn = 0; fn < NF; fn++)
                prow[fn * 16 + l15] = acc[fm][fn][r];
        }
}

// ---- fused split-K reduce + bias + bf16 h store + per-chunk stats partials ----
__global__ __launch_bounds__(256) void reduce_bias_stats(
    const float* __restrict__ partial, const float* __restrict__ bias,
    unsigned short* __restrict__ h, float* __restrict__ sp,
    int T, int O, int Npad, int KS, int hstride, int TO)
{
    __shared__ float redS[4][64], redS2[4][64];
    const int colL = threadIdx.x & 63;
    const int cr = threadIdx.x >> 6;
    const int col = blockIdx.x * 64 + colL;
    const int chunk = blockIdx.y;
    float s = 0.f, s2 = 0.f;
    if (col < TO) {
        int t = col / O, o = col - t * O;
        const size_t TNpad = (size_t)T * Npad;
        const size_t pcol = (size_t)t * Npad + o;
        const float bv = bias[col];
        const int row0 = chunk * 128 + cr * 32;
        for (int r = 0; r < 32; r++) {
            const int row = row0 + r;
            const float* p = partial + (size_t)row * TNpad + pcol;
            float v = bv;
            for (int ks = 0; ks < KS; ks++) v += p[(size_t)ks * BDIM * TNpad];
            h[(size_t)row * hstride + col] = f2bf(v);
            s += v; s2 += v * v;
        }
    }
    redS[cr][colL] = s; redS2[cr][colL] = s2;
    __syncthreads();
    if (cr == 0 && col < TO) {
        float ts  = redS[0][colL] + redS[1][colL] + redS[2][colL] + redS[3][colL];
        float ts2 = redS2[0][colL] + redS2[1][colL] + redS2[2][colL] + redS2[3][colL];
        sp[(size_t)chunk * 2 * TO + col] = ts;
        sp[(size_t)chunk * 2 * TO + TO + col] = ts2;
    }
}

// ---- fold NC chunk partials -> per-col scale/shift ----
__global__ __launch_bounds__(256) void bn_scaleN(const float* __restrict__ sp,
                                                 const float* __restrict__ g,
                                                 const float* __restrict__ bb,
                                                 float* __restrict__ ss, int TO, int NC) {
    int col = blockIdx.x * 256 + threadIdx.x;
    if (col >= TO) return;
    float s = 0.f, s2 = 0.f;
    for (int c = 0; c < NC; c++) {
        s  += sp[(size_t)c * 2 * TO + col];
        s2 += sp[(size_t)c * 2 * TO + TO + col];
    }
    float mu = s * (1.f / BDIM);
    float var = s2 * (1.f / BDIM) - mu * mu;  // biased, matches jnp.var
    float scale = rsqrtf(var + 1e-5f) * g[col];
    ss[col] = scale;
    ss[TO + col] = bb[col] - mu * scale;
}

// ---- vectorized BN+tanh+head for O=20 in-place stages (s4/s3) ----
template <int GPT>
__global__ __launch_bounds__(256) void bn_tanh_head_vec(
    unsigned short* hact, const float* __restrict__ ss,
    const float* __restrict__ hw, const float* __restrict__ hb,
    float* __restrict__ out,
    int T, int rowGran, int RPB, int hstride, int head_off)
{
    __shared__ float headAcc[256];
    const int tid = threadIdx.x;
    headAcc[tid] = 0.f;
    __syncthreads();
    const int b0 = blockIdx.x * RPB;

    uint2 hv[GPT];
    #pragma unroll
    for (int j = 0; j < GPT; j++) {
        int G = tid + j * 256;
        int r = G / rowGran, gg = G % rowGran;
        hv[j] = *(const uint2*)(hact + (size_t)(b0 + r) * hstride + gg * 4);
    }
    #pragma unroll
    for (int j = 0; j < GPT; j++) {
        int G = tid + j * 256;
        int r = G / rowGran, gg = G % rowGran;
        int c = gg * 4;
        float4 sc = *(const float4*)(ss + c);
        float4 sh = *(const float4*)(ss + hstride + c);
        float4 w4 = *(const float4*)(hw + c);
        union { unsigned short u[4]; uint2 v; } iv, ov;
        iv.v = hv[j];
        float a0 = fast_tanh(bf2f(iv.u[0]) * sc.x + sh.x);
        float a1 = fast_tanh(bf2f(iv.u[1]) * sc.y + sh.y);
        float a2 = fast_tanh(bf2f(iv.u[2]) * sc.z + sh.z);
        float a3 = fast_tanh(bf2f(iv.u[3]) * sc.w + sh.w);
        ov.u[0] = f2bf(a0); ov.u[1] = f2bf(a1); ov.u[2] = f2bf(a2); ov.u[3] = f2bf(a3);
        *(uint2*)(hact + (size_t)(b0 + r) * hstride + c) = ov.v;
        float partial = a0 * w4.x + a1 * w4.y + a2 * w4.z + a3 * w4.w;
        int t = gg / 5;
        atomicAdd(&headAcc[r * T + t], partial);
    }
    __syncthreads();
    if (tid < RPB * T) {
        int r = tid / T, t = tid % T;
        out[(size_t)(b0 + r) * OUTW + head_off + t] = headAcc[tid] + hb[t];
    }
}

// ---- BN + tanh + strided act store + head — WAVE variant ----
__global__ __launch_bounds__(256) void bn_tanh_head(
    const unsigned short* __restrict__ h, const float* __restrict__ ss,
    const float* __restrict__ hw, const float* __restrict__ hb,
    unsigned short* __restrict__ actOut, float* __restrict__ out,
    int T, int O, int hstride, int aRow, int GT, int GS, int head_off, int TO)
{
    int wid  = (blockIdx.x * 256 + threadIdx.x) >> 6;
    int lane = threadIdx.x & 63;
    int b = wid / T;
    int t = wid % T;
    const size_t hbase = (size_t)b * hstride + (size_t)t * O;
    const size_t abase = (size_t)b * aRow + (size_t)(t / GT) * GS + (size_t)(t % GT) * O;
    float hsum = 0.f;
    for (int o = lane; o < O; o += 64) {
        int col = t * O + o;
        float a = fast_tanh(bf2f(h[hbase + o]) * ss[col] + ss[TO + col]);
        if (actOut) actOut[abase + o] = f2bf(a);
        hsum += a * hw[col];
    }
    #pragma unroll
    for (int off = 32; off > 0; off >>= 1) hsum += __shfl_down(hsum, off, 64);
    if (lane == 0) out[(size_t)b * OUTW + head_off + t] = hsum + hb[t];
}

extern "C" void kernel_launch(void* const* d_in, const int* in_sizes, int n_in,
                              void* d_out, int out_size, void* d_ws, size_t ws_size,
                              hipStream_t stream)
{
    const float* x = (const float*)d_in[0];
    float* out = (float*)d_out;
    char* ws = (char*)d_ws;

    // ws layout (bytes)
    unsigned short* wbt  = (unsigned short*)(ws);              // 13,762,560
    unsigned short* ain0 = (unsigned short*)(ws + 13762560);   // 22,020,096 (2048x5376)
    unsigned short* bufA = (unsigned short*)(ws + 35782656);   // 20,971,520
    unsigned short* bufB = (unsigned short*)(ws + 56754176);   //  5,242,880
    unsigned short* ain1 = (unsigned short*)(ws + 61997056);   // 22,020,096
    unsigned short* bufC = (unsigned short*)(ws + 84017152);   //  5,046,272
    float*          ss   = (float*)(ws + 89063424);            //     40,960
    float*          sp0  = (float*)(ws + 89104384);            //    157,312 (16x2x1229)
    // overlays (all verified dead at use time):
    float* partial = (float*)(ws + 35782656);   // s1: 21 MB (=bufA), s0: 41.9 MB (bufA..ain1 head)
    float* sp4 = (float*)bufC;                  // 32x2x5120x4 = 1.31 MB (bufC free pre-s2)
    float* sp3 = (float*)bufC;                  // 0.33 MB
    float* sp2 = (float*)bufA;                  // 0.32 MB (act4 dead after s3 gemm)
    float* sp1 = (float*)bufB;                  // 0.32 MB (act3 dead after s2 gemm)
    unsigned short* xg = ain0 + 1232;           // full bf16 x copy, row stride 5376

    const float* W4 = (const float*)d_in[1];  const float* b4 = (const float*)d_in[2];
    const float* g4 = (const float*)d_in[3];  const float* bb4 = (const float*)d_in[4];
    const float* hw4 = (const float*)d_in[5]; const float* hb4 = (const float*)d_in[6];
    const float* W3 = (const float*)d_in[7];  const float* b3 = (const float*)d_in[8];
    const float* g3 = (const float*)d_in[9];  const float* bb3 = (const float*)d_in[10];
    const float* hw3 = (const float*)d_in[11]; const float* hb3 = (const float*)d_in[12];
    const float* W2 = (const float*)d_in[13]; const float* b2 = (const float*)d_in[14];
    const float* g2 = (const float*)d_in[15]; const float* bb2 = (const float*)d_in[16];
    const float* hw2 = (const float*)d_in[17]; const float* hb2 = (const float*)d_in[18];
    const float* W1 = (const float*)d_in[19]; const float* b1 = (const float*)d_in[20];
    const float* g1 = (const float*)d_in[21]; const float* bb1 = (const float*)d_in[22];
    const float* hw1 = (const float*)d_in[23]; const float* hb1 = (const float*)d_in[24];
    const float* W0 = (const float*)d_in[25]; const float* b0_ = (const float*)d_in[26];
    const float* g0 = (const float*)d_in[27]; const float* bb0 = (const float*)d_in[28];
    const float* hw0 = (const float*)d_in[29]; const float* hb0 = (const float*)d_in[30];

    // 1-2: packs + weight conversions (s4..s1)
    pack_x<<<(BDIM * 512 + BDIM * 24 + 255) / 256, 256, 0, stream>>>(x, ain0, ain1);
    cvt_w_all<<<2896, 256, 0, stream>>>(W4, W3, W2, W1, wbt);

    // s4: T=256 I=16 O=20 Kpad=32, WbT @0
    gemm_small<32, 32><<<dim3(1, 32, 256), 256, 0, stream>>>(nullptr, xg, wbt, b4, bufA,
                                                             sp4, 256, 16, 20, 0, 16, 32, 5120, 5120);
    bn_scaleN<<<20, 256, 0, stream>>>(sp4, g4, bb4, ss, 5120, 32);
    bn_tanh_head_vec<5><<<BDIM, 256, 0, stream>>>(bufA, ss, hw4, hb4, out, 256, 1280, 1, 5120, 0);

    // s3: T=64 I=144 O=20 Kpad=192, WbT @163840
    gemm_small<32, 64><<<dim3(1, 32, 64), 256, 0, stream>>>(bufA, xg, wbt + 163840, b3, bufB,
                                                            sp3, 64, 144, 20, 80, 64, 192, 1280, 1280);
    bn_scaleN<<<5, 256, 0, stream>>>(sp3, g3, bb3, ss, 1280, 32);
    bn_tanh_head_vec<5><<<BDIM / 4, 256, 0, stream>>>(bufB, ss, hw3, hb3, out, 64, 320, 4, 1280, 256);

    // s2: T=16 I=336 O=77 Kpad=384, WbT @409600
    gemm_small<64, 64><<<dim3(2, 32, 16), 256, 0, stream>>>(bufB, xg, wbt + 409600, b2, bufC,
                                                            sp2, 16, 336, 77, 80, 256, 384, 1232, 1232);
    bn_scaleN<<<5, 256, 0, stream>>>(sp2, g2, bb2, ss, 1232, 32);
    bn_tanh_head<<<BDIM * 16 / 4, 256, 0, stream>>>(bufC, ss, hw2, hb2,
                                                    ain1, out, 16, 77, 1232, 5376, 4, 1344, 320, 1232);

    // s1: T=4 I=1332 O=308 Kpad=1344 Npad=320 KS=2, WbT @882688
    // swizzled 1D grid: nTiles=5, TKS=T*KS=8, blocks = 5*16*8 = 640
    gemm_split<64><<<640, 256, 0, stream>>>(ain1, wbt + 882688, partial,
                                            5376, 1344, 1344, 320, 2, 1280, 5, 8);
    cvt_w<<<dim3(168, 40, 1), 256, 0, stream>>>(W0, wbt, 5328, 1229, 1280, 5376);  // overlaps s1 tail
    reduce_bias_stats<<<dim3(20, 16), 256, 0, stream>>>(partial, b1, bufC, sp1,
                                                        4, 308, 320, 2, 1232, 1232);
    bn_scaleN<<<5, 256, 0, stream>>>(sp1, g1, bb1, ss, 1232, 16);
    bn_tanh_head<<<BDIM * 4 / 4, 256, 0, stream>>>(bufC, ss, hw1, hb1,
                                                   ain0, out, 4, 308, 1232, 5376, 4, 0, 336, 1232);

    // s0: T=1 I=5328 O=1229 Kpad=5376 Npad=1280 KS=4
    // swizzled 1D grid: nTiles=10, TKS=4, blocks = 10*16*4 = 640
    gemm_split<128><<<640, 256, 0, stream>>>(ain0, wbt, partial,
                                             5376, 0, 5376, 1280, 4, 1280, 10, 4);
    reduce_bias_stats<<<dim3(20, 16), 256, 0, stream>>>(partial, b0_, bufC, sp0,
                                                        1, 1229, 1280, 4, 1232, 1229);
    bn_scaleN<<<5, 256, 0, stream>>>(sp0, g0, bb0, ss, 1229, 16);
    bn_tanh_head<<<BDIM / 4, 256, 0, stream>>>(bufC, ss, hw0, hb0,
                                               nullptr, out, 1, 1229, 1232, 1232, 1, 0, 340, 1229);
}